// Round 6
// baseline (182.977 us; speedup 1.0000x reference)
//
#include <hip/hip_runtime.h>
#include <hip/hip_bf16.h>

#define B_ 8
#define N_ 512
#define NN (N_*N_)

typedef __attribute__((ext_vector_type(8))) __bf16 bf16x8;
typedef __attribute__((ext_vector_type(4))) float f32x4;

// ---------------- stage 1: fused  zero-out | weight-prep | node MLP ---------
// blocks [0,4096): node MLP row = blk (128 thr)
// blocks [4096,4864): transpose uw0/uw1 -> bf16 w0t/w1t
// blocks [4864,4872): zero d_out
__global__ __launch_bounds__(128) void k_stage1(
    const float* __restrict__ coords,
    const float* __restrict__ fw0, const float* __restrict__ fb0,
    const float* __restrict__ fw1, const float* __restrict__ fb1,
    const float* __restrict__ aw0,
    const float* __restrict__ uw0, const float* __restrict__ uw1,
    float* __restrict__ h, __bf16* __restrict__ h_t, float* __restrict__ g,
    __bf16* __restrict__ w0t, __bf16* __restrict__ w1t,
    float* __restrict__ out, int out_size)
{
    const int blk = blockIdx.x;
    const int t = threadIdx.x;

    if (blk < 4096) {
        // ---- node feature MLP: (3) -> 64 -> 128; also g = c . aw0[3:6] ----
        int row = blk;                 // b*512 + n
        int b = row >> 9;
        int n = row & 511;
        __shared__ float c[3];
        __shared__ float hid[64];
        if (t < 3) c[t] = coords[row * 3 + t];
        __syncthreads();
        if (t < 64) {
            float v = fb0[t];
            v += c[0] * fw0[0 * 64 + t];
            v += c[1] * fw0[1 * 64 + t];
            v += c[2] * fw0[2 * 64 + t];
            hid[t] = fmaxf(v, 0.0f);
            g[((size_t)row << 6) + t] = c[0] * aw0[3 * 64 + t]
                                      + c[1] * aw0[4 * 64 + t]
                                      + c[2] * aw0[5 * 64 + t];
        }
        __syncthreads();
        float acc = fb1[t];
#pragma unroll
        for (int k = 0; k < 64; ++k) acc += hid[k] * fw1[k * 128 + t];
        float r = fmaxf(acc, 0.0f);
        h[(size_t)row * 128 + t] = r;
        h_t[(size_t)(b * 128 + t) * 512 + n] = (__bf16)r;
    } else if (blk < 4864) {
        // ---- weight prep ----
        int id = (blk - 4096) * 128 + t;    // 0..98303
        if (id < 65536) {
            int c = id >> 8, k = id & 255;
            int src = (k < 128) ? k : (k + 3);
            w0t[(size_t)c * 256 + k] = (__bf16)uw0[(size_t)src * 256 + c];
        } else {
            int id2 = id - 65536;
            int c = id2 >> 8, k = id2 & 255;
            w1t[(size_t)c * 256 + k] = (__bf16)uw1[(size_t)k * 128 + c];
        }
    } else {
        // ---- zero output ----
        int i = (blk - 4864) * 128 + t;
        if (i < out_size) out[i] = 0.0f;
    }
}

// ---------------- adjacency MLP via bf16 MFMA, transposed epilogue ----------
// grid 2048 x 256thr: blk -> (b, i-group of 4, j-half). Wave owns one i and
// 16 j-tiles (256 pairs). 32 waves/CU grid max at VGPR<=64.
__global__ __launch_bounds__(256) void k_adj(
    const float* __restrict__ coords, const float* __restrict__ g,
    const float* __restrict__ aw0, const float* __restrict__ ab0,
    const float* __restrict__ aw1, const float* __restrict__ ab1,
    const float* __restrict__ aw2, const float* __restrict__ ab2,
    __bf16* __restrict__ A)
{
    const int tid = threadIdx.x;
    const int l = tid & 63;          // lane
    const int wave = tid >> 6;       // 0..3
    const int q = l >> 4;            // quad 0..3
    const int m = l & 15;            // 0..15
    const int b = blockIdx.x >> 8;
    const int half = blockIdx.x & 1;
    const int i = (((blockIdx.x >> 1) & 127) << 2) + wave;

    // wave-uniform c_i folded into per-lane layer-0 offsets
    const float* ci = coords + (size_t)(b * N_ + i) * 3;
    const float ci0 = ci[0], ci1 = ci[1], ci2 = ci[2];

    float o[2][8];
#pragma unroll
    for (int s = 0; s < 2; ++s)
#pragma unroll
        for (int j = 0; j < 8; ++j) {
            int c = s * 32 + q * 8 + j;
            o[s][j] = ab0[c] + ci0 * aw0[0 * 64 + c] + ci1 * aw0[1 * 64 + c]
                             + ci2 * aw0[2 * 64 + c];
        }

    // aw1 fragments (A-operand of the transposed MFMA)
    bf16x8 bf[2][4];
#pragma unroll
    for (int s = 0; s < 2; ++s)
#pragma unroll
        for (int ct = 0; ct < 4; ++ct)
#pragma unroll
            for (int j = 0; j < 8; ++j)
                bf[s][ct][j] = (__bf16)aw1[(s * 32 + q * 8 + j) * 64 + ct * 16 + m];

    float ab1e[4][4], aw2e[4][4];
#pragma unroll
    for (int ct = 0; ct < 4; ++ct)
#pragma unroll
        for (int r = 0; r < 4; ++r) {
            int ch = ct * 16 + q * 4 + r;
            ab1e[ct][r] = ab1[ch];
            aw2e[ct][r] = aw2[ch];
        }
    const float ab2s = ab2[0];

    __bf16* Arow = A + ((size_t)(b * N_ + i) << 9) + half * 256;
    const float* grow0 = g + ((size_t)(b * N_ + half * 256 + m) << 6);

#pragma unroll 1
    for (int t = 0; t < 16; ++t) {
        const float* grow = grow0 + (size_t)t * (16 * 64);
        f32x4 ga0 = *(const f32x4*)(grow + q * 8);
        f32x4 ga1 = *(const f32x4*)(grow + q * 8 + 4);
        f32x4 gb0 = *(const f32x4*)(grow + 32 + q * 8);
        f32x4 gb1 = *(const f32x4*)(grow + 32 + q * 8 + 4);

        bf16x8 a0, a1;
#pragma unroll
        for (int j = 0; j < 4; ++j) {
            a0[j]     = (__bf16)fmaxf(o[0][j]     + ga0[j], 0.0f);
            a0[4 + j] = (__bf16)fmaxf(o[0][4 + j] + ga1[j], 0.0f);
            a1[j]     = (__bf16)fmaxf(o[1][j]     + gb0[j], 0.0f);
            a1[4 + j] = (__bf16)fmaxf(o[1][4 + j] + gb1[j], 0.0f);
        }

        // layer 1 transposed: lane holds 16 output channels of ONE pair
        float p0, p1, p2, p3;
        {
            f32x4 c0v = {ab1e[0][0], ab1e[0][1], ab1e[0][2], ab1e[0][3]};
            c0v = __builtin_amdgcn_mfma_f32_16x16x32_bf16(bf[0][0], a0, c0v, 0, 0, 0);
            c0v = __builtin_amdgcn_mfma_f32_16x16x32_bf16(bf[1][0], a1, c0v, 0, 0, 0);
            f32x4 c1v = {ab1e[1][0], ab1e[1][1], ab1e[1][2], ab1e[1][3]};
            c1v = __builtin_amdgcn_mfma_f32_16x16x32_bf16(bf[0][1], a0, c1v, 0, 0, 0);
            c1v = __builtin_amdgcn_mfma_f32_16x16x32_bf16(bf[1][1], a1, c1v, 0, 0, 0);
            f32x4 c2v = {ab1e[2][0], ab1e[2][1], ab1e[2][2], ab1e[2][3]};
            c2v = __builtin_amdgcn_mfma_f32_16x16x32_bf16(bf[0][2], a0, c2v, 0, 0, 0);
            c2v = __builtin_amdgcn_mfma_f32_16x16x32_bf16(bf[1][2], a1, c2v, 0, 0, 0);
            f32x4 c3v = {ab1e[3][0], ab1e[3][1], ab1e[3][2], ab1e[3][3]};
            c3v = __builtin_amdgcn_mfma_f32_16x16x32_bf16(bf[0][3], a0, c3v, 0, 0, 0);
            c3v = __builtin_amdgcn_mfma_f32_16x16x32_bf16(bf[1][3], a1, c3v, 0, 0, 0);
            p0 = fmaxf(c0v[0], 0.f) * aw2e[0][0] + fmaxf(c0v[1], 0.f) * aw2e[0][1]
               + fmaxf(c0v[2], 0.f) * aw2e[0][2] + fmaxf(c0v[3], 0.f) * aw2e[0][3];
            p1 = fmaxf(c1v[0], 0.f) * aw2e[1][0] + fmaxf(c1v[1], 0.f) * aw2e[1][1]
               + fmaxf(c1v[2], 0.f) * aw2e[1][2] + fmaxf(c1v[3], 0.f) * aw2e[1][3];
            p2 = fmaxf(c2v[0], 0.f) * aw2e[2][0] + fmaxf(c2v[1], 0.f) * aw2e[2][1]
               + fmaxf(c2v[2], 0.f) * aw2e[2][2] + fmaxf(c2v[3], 0.f) * aw2e[2][3];
            p3 = fmaxf(c3v[0], 0.f) * aw2e[3][0] + fmaxf(c3v[1], 0.f) * aw2e[3][1]
               + fmaxf(c3v[2], 0.f) * aw2e[3][2] + fmaxf(c3v[3], 0.f) * aw2e[3][3];
        }
        float p = (p0 + p1) + (p2 + p3);
        p += __shfl_xor(p, 16, 64);
        p += __shfl_xor(p, 32, 64);
        if (l < 16) Arow[(t << 4) + l] = (__bf16)fmaxf(ab2s + p, 0.0f);
    }
}

// ---------------- V = A @ h via bf16 MFMA, one wave per 16x16 tile ----------
// grid 2048 x 64 thr: blk -> (b, row-tile 0..31, n-tile 0..7). 8 waves/CU.
__global__ __launch_bounds__(64) void k_aggregate(
    const __bf16* __restrict__ A, const __bf16* __restrict__ h_t,
    float* __restrict__ V)
{
    const int l = threadIdx.x;
    const int q = l >> 4;
    const int m = l & 15;
    const int b = blockIdx.x >> 8;
    const int rest = blockIdx.x & 255;
    const int row0 = (rest >> 3) << 4;
    const int nt = rest & 7;

    const __bf16* Ar = A + ((size_t)b << 18) + (size_t)(row0 + m) * 512 + q * 8;
    const __bf16* hp = h_t + ((size_t)b << 16) + (size_t)(nt * 16 + m) * 512 + q * 8;

    f32x4 acc = {0.f, 0.f, 0.f, 0.f};
#pragma unroll 4
    for (int kt = 0; kt < 16; ++kt) {
        bf16x8 av = *(const bf16x8*)(Ar + kt * 32);
        bf16x8 bv = *(const bf16x8*)(hp + kt * 32);
        acc = __builtin_amdgcn_mfma_f32_16x16x32_bf16(av, bv, acc, 0, 0, 0);
    }
    float* Vb = V + ((size_t)(b * N_ + row0) << 7);
#pragma unroll
    for (int r = 0; r < 4; ++r)
        Vb[(size_t)(q * 4 + r) * 128 + nt * 16 + m] = acc[r];
}

// ---------------- update MLP (259 -> 256 -> 128) via MFMA + max pool --------
__global__ __launch_bounds__(512) void k_update(
    const float* __restrict__ h, const float* __restrict__ coords,
    const float* __restrict__ V,
    const float* __restrict__ uw0, const float* __restrict__ ub0,
    const __bf16* __restrict__ w0t, const __bf16* __restrict__ w1t,
    const float* __restrict__ ub1,
    float* __restrict__ out)
{
    const int t = threadIdx.x;
    const int g = t >> 6;            // wave 0..7
    const int l = t & 63;
    const int q = l >> 4;
    const int m = l & 15;
    const int row0 = blockIdx.x << 4;   // 16 rows, same b
    const int b = row0 >> 9;

    __shared__ __align__(16) __bf16 act[16][256];  // [row][k], k=[h|V]
    __shared__ __align__(16) __bf16 u1[16][256];
    __shared__ float cds[16][4];

#pragma unroll 1
    for (int r = 0; r < 16; ++r) {
        int row = row0 + r;
        if (t < 128) act[r][t] = (__bf16)h[((size_t)row << 7) + t];
        else if (t < 256) act[r][t] = (__bf16)V[((size_t)row << 7) + (t - 128)];
    }
    if (t < 48) {
        int r = t / 3, d = t - 3 * r;
        cds[r][d] = coords[(size_t)(row0 + r) * 3 + d];
    }
    __syncthreads();

    bf16x8 af[8];
#pragma unroll
    for (int ch = 0; ch < 8; ++ch)
        af[ch] = *(const bf16x8*)&act[m][q * 8 + 32 * ch];

#pragma unroll
    for (int ct = 0; ct < 2; ++ct) {
        const int c = g * 32 + ct * 16 + m;
        const float wx = uw0[128 * 256 + c];
        const float wy = uw0[129 * 256 + c];
        const float wz = uw0[130 * 256 + c];
        const float bias = ub0[c];
        f32x4 acc;
#pragma unroll
        for (int r = 0; r < 4; ++r)
            acc[r] = bias + cds[q * 4 + r][0] * wx + cds[q * 4 + r][1] * wy
                          + cds[q * 4 + r][2] * wz;
        const __bf16* wp = w0t + (size_t)c * 256 + q * 8;
#pragma unroll
        for (int ch = 0; ch < 8; ++ch) {
            bf16x8 bfr = *(const bf16x8*)(wp + 32 * ch);
            acc = __builtin_amdgcn_mfma_f32_16x16x32_bf16(af[ch], bfr, acc, 0, 0, 0);
        }
#pragma unroll
        for (int r = 0; r < 4; ++r)
            u1[q * 4 + r][c] = (__bf16)fmaxf(acc[r], 0.0f);
    }
    __syncthreads();

    bf16x8 af2[8];
#pragma unroll
    for (int ch = 0; ch < 8; ++ch)
        af2[ch] = *(const bf16x8*)&u1[m][q * 8 + 32 * ch];
    {
        const int c = g * 16 + m;
        float bias = ub1[c];
        f32x4 acc = {bias, bias, bias, bias};
        const __bf16* wp = w1t + (size_t)c * 256 + q * 8;
#pragma unroll
        for (int ch = 0; ch < 8; ++ch) {
            bf16x8 bfr = *(const bf16x8*)(wp + 32 * ch);
            acc = __builtin_amdgcn_mfma_f32_16x16x32_bf16(af2[ch], bfr, acc, 0, 0, 0);
        }
        float mx = fmaxf(fmaxf(acc[0], acc[1]), fmaxf(acc[2], acc[3]));
        mx = fmaxf(mx, 0.0f);
        mx = fmaxf(mx, __shfl_xor(mx, 16, 64));
        mx = fmaxf(mx, __shfl_xor(mx, 32, 64));
        if (l < 16)
            atomicMax((int*)(out + ((size_t)b << 7) + c), __float_as_int(mx));
    }
}

extern "C" void kernel_launch(void* const* d_in, const int* in_sizes, int n_in,
                              void* d_out, int out_size, void* d_ws, size_t ws_size,
                              hipStream_t stream)
{
    const float* coords = (const float*)d_in[0];
    const float* fw0 = (const float*)d_in[1];
    const float* fb0 = (const float*)d_in[2];
    const float* fw1 = (const float*)d_in[3];
    const float* fb1 = (const float*)d_in[4];
    const float* aw0 = (const float*)d_in[5];
    const float* ab0 = (const float*)d_in[6];
    const float* aw1 = (const float*)d_in[7];
    const float* ab1 = (const float*)d_in[8];
    const float* aw2 = (const float*)d_in[9];
    const float* ab2 = (const float*)d_in[10];
    const float* uw0 = (const float*)d_in[11];
    const float* ub0 = (const float*)d_in[12];
    const float* uw1 = (const float*)d_in[13];
    const float* ub1 = (const float*)d_in[14];
    float* out = (float*)d_out;

    // workspace layout
    char* ws = (char*)d_ws;
    float* h    = (float*)(ws);                        // 2 MB fp32
    __bf16* A   = (__bf16*)(ws + (2u << 20));          // 4 MB bf16
    float* V    = (float*)(ws + (6u << 20));           // 2 MB fp32
    __bf16* h_t = (__bf16*)(ws + (8u << 20));          // 1 MB bf16
    float* g    = (float*)(ws + (9u << 20));           // 1 MB fp32
    __bf16* w0t = (__bf16*)(ws + (10u << 20));         // 128 KB
    __bf16* w1t = (__bf16*)(ws + (10u << 20) + (128u << 10)); // 64 KB

    k_stage1<<<4872, 128, 0, stream>>>(coords, fw0, fb0, fw1, fb1, aw0, uw0, uw1,
                                       h, h_t, g, w0t, w1t, out, out_size);
    k_adj<<<2048, 256, 0, stream>>>(coords, g, aw0, ab0, aw1, ab1, aw2, ab2, A);
    k_aggregate<<<2048, 64, 0, stream>>>(A, h_t, V);
    k_update<<<B_ * N_ / 16, 512, 0, stream>>>(h, coords, V, uw0, ub0, w0t, w1t, ub1, out);
}

// Round 8
// 181.838 us; speedup vs baseline: 1.0063x; 1.0063x over previous
//
#include <hip/hip_runtime.h>
#include <hip/hip_bf16.h>

#define B_ 8
#define N_ 512

typedef __attribute__((ext_vector_type(8))) __bf16 bf16x8;
typedef __attribute__((ext_vector_type(4))) float f32x4;
typedef __attribute__((ext_vector_type(4))) unsigned int u32x4;

// pack two fp32 into bf16x2 by truncation: 1 v_perm_b32
__device__ __forceinline__ unsigned pk_bf16(float hi, float lo) {
    return __builtin_amdgcn_perm(__builtin_bit_cast(unsigned, hi),
                                 __builtin_bit_cast(unsigned, lo), 0x07060302u);
}

// ---------------- stage 1: fused node-MLP | weight-prep | zero-out ----------
// [0,4096)      node MLP (h_bf, h_t, g)
// [4096,4864)   w0t/w1t transpose->bf16
// [4864,4896)   aw1p fragment pack
// [4896,4904)   zero d_out
// 4904          eb/ew epilogue constants
__global__ __launch_bounds__(128) void k_stage1(
    const float* __restrict__ coords,
    const float* __restrict__ fw0, const float* __restrict__ fb0,
    const float* __restrict__ fw1, const float* __restrict__ fb1,
    const float* __restrict__ aw0, const float* __restrict__ aw1,
    const float* __restrict__ ab1, const float* __restrict__ aw2,
    const float* __restrict__ uw0, const float* __restrict__ uw1,
    __bf16* __restrict__ h_bf, __bf16* __restrict__ h_t, float* __restrict__ g,
    __bf16* __restrict__ w0t, __bf16* __restrict__ w1t,
    __bf16* __restrict__ aw1p, float* __restrict__ eb, float* __restrict__ ew,
    float* __restrict__ out, int out_size)
{
    const int blk = blockIdx.x;
    const int t = threadIdx.x;

    if (blk < 4096) {
        int row = blk;                 // b*512 + n
        int b = row >> 9;
        int n = row & 511;
        __shared__ float c[3];
        __shared__ float hid[64];
        if (t < 3) c[t] = coords[row * 3 + t];
        __syncthreads();
        if (t < 64) {
            float v = fb0[t];
            v += c[0] * fw0[0 * 64 + t];
            v += c[1] * fw0[1 * 64 + t];
            v += c[2] * fw0[2 * 64 + t];
            hid[t] = fmaxf(v, 0.0f);
            g[((size_t)row << 6) + t] = c[0] * aw0[3 * 64 + t]
                                      + c[1] * aw0[4 * 64 + t]
                                      + c[2] * aw0[5 * 64 + t];
        }
        __syncthreads();
        float acc = fb1[t];
#pragma unroll
        for (int k = 0; k < 64; ++k) acc += hid[k] * fw1[k * 128 + t];
        float r = fmaxf(acc, 0.0f);
        h_bf[((size_t)row << 7) + t] = (__bf16)r;
        h_t[(size_t)(b * 128 + t) * 512 + n] = (__bf16)r;
    } else if (blk < 4864) {
        int id = (blk - 4096) * 128 + t;    // 0..98303
        if (id < 65536) {
            int c = id >> 8, k = id & 255;
            int src = (k < 128) ? k : (k + 3);
            w0t[(size_t)c * 256 + k] = (__bf16)uw0[(size_t)src * 256 + c];
        } else {
            int id2 = id - 65536;
            int c = id2 >> 8, k = id2 & 255;
            w1t[(size_t)c * 256 + k] = (__bf16)uw1[(size_t)k * 128 + c];
        }
    } else if (blk < 4896) {
        // aw1p[s*2048 + ct*512 + q*128 + m*8 + j] = aw1[(s*32+q*8+j)*64 + ct*16+m]
        int id = (blk - 4864) * 128 + t;    // 0..4095
        int j = id & 7, m = (id >> 3) & 15, q = (id >> 7) & 3;
        int ct = (id >> 9) & 3, s = (id >> 11) & 1;
        aw1p[id] = (__bf16)aw1[(s * 32 + q * 8 + j) * 64 + ct * 16 + m];
    } else if (blk < 4904) {
        int i = (blk - 4896) * 128 + t;
        if (i < out_size) out[i] = 0.0f;
    } else {
        if (t < 64) {
            int q = t >> 4, ct = (t >> 2) & 3, r = t & 3;
            int ch = ct * 16 + q * 4 + r;
            eb[t] = ab1[ch];
            ew[t] = aw2[ch];
        }
    }
}

// ---------------- adjacency MLP via bf16 MFMA, transposed epilogue ----------
// 1024 blocks x 4 waves; wave owns one i-row, 32 tiles of 16 j.
// Pre-packed weights; v_perm truncation packing; g prefetch 1 tile ahead.
__global__ __launch_bounds__(256) void k_adj(
    const float* __restrict__ coords, const float* __restrict__ g,
    const float* __restrict__ aw0, const float* __restrict__ ab0,
    const __bf16* __restrict__ aw1p,
    const float* __restrict__ eb, const float* __restrict__ ew,
    const float* __restrict__ ab2,
    __bf16* __restrict__ A)
{
    const int tid = threadIdx.x;
    const int l = tid & 63;
    const int wave = tid >> 6;
    const int q = l >> 4;
    const int m = l & 15;
    const int b = blockIdx.x >> 7;
    const int i = ((blockIdx.x & 127) << 2) + wave;

    const float* ci = coords + (size_t)(b * N_ + i) * 3;
    const float ci0 = ci[0], ci1 = ci[1], ci2 = ci[2];

    // layer-0 per-lane offsets o[s-half]: vectorized prologue
    f32x4 o0a, o0b, o1a, o1b;
    {
        int base = q * 8;
        f32x4 bb0 = *(const f32x4*)(ab0 + base);
        f32x4 bb1 = *(const f32x4*)(ab0 + base + 4);
        f32x4 wa0 = *(const f32x4*)(aw0 + base);
        f32x4 wa1 = *(const f32x4*)(aw0 + base + 4);
        f32x4 wb0 = *(const f32x4*)(aw0 + 64 + base);
        f32x4 wb1 = *(const f32x4*)(aw0 + 64 + base + 4);
        f32x4 wc0 = *(const f32x4*)(aw0 + 128 + base);
        f32x4 wc1 = *(const f32x4*)(aw0 + 128 + base + 4);
        o0a = bb0 + ci0 * wa0 + ci1 * wb0 + ci2 * wc0;
        o0b = bb1 + ci0 * wa1 + ci1 * wb1 + ci2 * wc1;
        base = 32 + q * 8;
        bb0 = *(const f32x4*)(ab0 + base);
        bb1 = *(const f32x4*)(ab0 + base + 4);
        wa0 = *(const f32x4*)(aw0 + base);
        wa1 = *(const f32x4*)(aw0 + base + 4);
        wb0 = *(const f32x4*)(aw0 + 64 + base);
        wb1 = *(const f32x4*)(aw0 + 64 + base + 4);
        wc0 = *(const f32x4*)(aw0 + 128 + base);
        wc1 = *(const f32x4*)(aw0 + 128 + base + 4);
        o1a = bb0 + ci0 * wa0 + ci1 * wb0 + ci2 * wc0;
        o1b = bb1 + ci0 * wa1 + ci1 * wb1 + ci2 * wc1;
    }

    // aw1 fragments: single 16B load each
    bf16x8 bfr[2][4];
#pragma unroll
    for (int s = 0; s < 2; ++s)
#pragma unroll
        for (int ct = 0; ct < 4; ++ct)
            bfr[s][ct] = *(const bf16x8*)(aw1p + s * 2048 + ct * 512 + q * 128 + m * 8);

    f32x4 ab1q[4], ewq[4];
#pragma unroll
    for (int ct = 0; ct < 4; ++ct) {
        ab1q[ct] = *(const f32x4*)(eb + q * 16 + ct * 4);
        ewq[ct] = *(const f32x4*)(ew + q * 16 + ct * 4);
    }
    const float ab2s = ab2[0];

    __bf16* Arow = A + ((size_t)(b * N_ + i) << 9);
    const float* gbase = g + (((size_t)(b * N_) + m) << 6);

    // prefetch tile 0
    f32x4 ga0, ga1, gb0, gb1;
    {
        const float* gr = gbase;
        ga0 = *(const f32x4*)(gr + q * 8);
        ga1 = *(const f32x4*)(gr + q * 8 + 4);
        gb0 = *(const f32x4*)(gr + 32 + q * 8);
        gb1 = *(const f32x4*)(gr + 32 + q * 8 + 4);
    }

#pragma unroll 1
    for (int t = 0; t < 32; ++t) {
        // prefetch next tile (wraps at the end; redundant last load is harmless)
        int tn = (t + 1) & 31;
        const float* gn = gbase + (size_t)tn * 1024;
        f32x4 na0 = *(const f32x4*)(gn + q * 8);
        f32x4 na1 = *(const f32x4*)(gn + q * 8 + 4);
        f32x4 nb0 = *(const f32x4*)(gn + 32 + q * 8);
        f32x4 nb1 = *(const f32x4*)(gn + 32 + q * 8 + 4);

        // layer 0: relu(o + g), pack to bf16 via v_perm truncation
        f32x4 v0, v1, v2, v3;
#pragma unroll
        for (int j = 0; j < 4; ++j) {
            v0[j] = fmaxf(o0a[j] + ga0[j], 0.0f);
            v1[j] = fmaxf(o0b[j] + ga1[j], 0.0f);
            v2[j] = fmaxf(o1a[j] + gb0[j], 0.0f);
            v3[j] = fmaxf(o1b[j] + gb1[j], 0.0f);
        }
        u32x4 pa, pb;
        pa[0] = pk_bf16(v0[1], v0[0]); pa[1] = pk_bf16(v0[3], v0[2]);
        pa[2] = pk_bf16(v1[1], v1[0]); pa[3] = pk_bf16(v1[3], v1[2]);
        pb[0] = pk_bf16(v2[1], v2[0]); pb[1] = pk_bf16(v2[3], v2[2]);
        pb[2] = pk_bf16(v3[1], v3[0]); pb[3] = pk_bf16(v3[3], v3[2]);
        bf16x8 a0 = __builtin_bit_cast(bf16x8, pa);
        bf16x8 a1 = __builtin_bit_cast(bf16x8, pb);

        // layer 1 transposed MFMA; ab1 folded into C-init
        float p0, p1, p2, p3;
        {
            f32x4 c0v = ab1q[0];
            c0v = __builtin_amdgcn_mfma_f32_16x16x32_bf16(bfr[0][0], a0, c0v, 0, 0, 0);
            c0v = __builtin_amdgcn_mfma_f32_16x16x32_bf16(bfr[1][0], a1, c0v, 0, 0, 0);
            f32x4 c1v = ab1q[1];
            c1v = __builtin_amdgcn_mfma_f32_16x16x32_bf16(bfr[0][1], a0, c1v, 0, 0, 0);
            c1v = __builtin_amdgcn_mfma_f32_16x16x32_bf16(bfr[1][1], a1, c1v, 0, 0, 0);
            f32x4 c2v = ab1q[2];
            c2v = __builtin_amdgcn_mfma_f32_16x16x32_bf16(bfr[0][2], a0, c2v, 0, 0, 0);
            c2v = __builtin_amdgcn_mfma_f32_16x16x32_bf16(bfr[1][2], a1, c2v, 0, 0, 0);
            f32x4 c3v = ab1q[3];
            c3v = __builtin_amdgcn_mfma_f32_16x16x32_bf16(bfr[0][3], a0, c3v, 0, 0, 0);
            c3v = __builtin_amdgcn_mfma_f32_16x16x32_bf16(bfr[1][3], a1, c3v, 0, 0, 0);
            p0 = fmaxf(c0v[0], 0.f) * ewq[0][0] + fmaxf(c0v[1], 0.f) * ewq[0][1]
               + fmaxf(c0v[2], 0.f) * ewq[0][2] + fmaxf(c0v[3], 0.f) * ewq[0][3];
            p1 = fmaxf(c1v[0], 0.f) * ewq[1][0] + fmaxf(c1v[1], 0.f) * ewq[1][1]
               + fmaxf(c1v[2], 0.f) * ewq[1][2] + fmaxf(c1v[3], 0.f) * ewq[1][3];
            p2 = fmaxf(c2v[0], 0.f) * ewq[2][0] + fmaxf(c2v[1], 0.f) * ewq[2][1]
               + fmaxf(c2v[2], 0.f) * ewq[2][2] + fmaxf(c2v[3], 0.f) * ewq[2][3];
            p3 = fmaxf(c3v[0], 0.f) * ewq[3][0] + fmaxf(c3v[1], 0.f) * ewq[3][1]
               + fmaxf(c3v[2], 0.f) * ewq[3][2] + fmaxf(c3v[3], 0.f) * ewq[3][3];
        }
        float p = (p0 + p1) + (p2 + p3);
        p += __shfl_xor(p, 16, 64);
        p += __shfl_xor(p, 32, 64);
        if (l < 16) Arow[(t << 4) + l] = (__bf16)fmaxf(ab2s + p, 0.0f);

        ga0 = na0; ga1 = na1; gb0 = nb0; gb1 = nb1;
    }
}

// ---------------- fused  V = A@h (MFMA)  +  update MLP  +  max pool ---------
// 256 blocks x 512 thr (8 waves). Wave gw computes V n-tile gw (16 rows x 16
// cols, K=512) straight into LDS act; h staged from h_bf; then 259->256->128
// MLP via MFMA; block max -> one atomic per col.
// NOTE: row0 here is the GLOBAL row (b*512 + local) — A is indexed by global
// row directly; do NOT add b<<18 again (that was R7's OOB bug).
__global__ __launch_bounds__(512) void k_aggupd(
    const __bf16* __restrict__ A, const __bf16* __restrict__ h_t,
    const __bf16* __restrict__ h_bf, const float* __restrict__ coords,
    const float* __restrict__ uw0, const float* __restrict__ ub0,
    const __bf16* __restrict__ w0t, const __bf16* __restrict__ w1t,
    const float* __restrict__ ub1,
    float* __restrict__ out)
{
    const int t = threadIdx.x;
    const int gw = t >> 6;           // wave 0..7
    const int l = t & 63;
    const int q = l >> 4;
    const int m = l & 15;
    const int row0 = blockIdx.x << 4;   // 16 GLOBAL rows, same b
    const int b = row0 >> 9;

    __shared__ __align__(16) __bf16 act[16][256];  // [row][k], k=[h|V]
    __shared__ __align__(16) __bf16 u1[16][256];
    __shared__ float cds[16][4];

    // issue staging loads early
    unsigned long long hv = *(const unsigned long long*)
        (h_bf + ((size_t)(row0 + (t >> 5)) << 7) + (t & 31) * 4);
    float cdv = 0.0f;
    if (t < 48) cdv = coords[(size_t)row0 * 3 + t];

    // ---- aggregate: V tile via MFMA (A indexed by global row!) ----
    const __bf16* Ar = A + (size_t)(row0 + m) * 512 + q * 8;
    const __bf16* hp = h_t + ((size_t)b << 16) + (size_t)(gw * 16 + m) * 512 + q * 8;
    f32x4 acc = {0.f, 0.f, 0.f, 0.f};
#pragma unroll 4
    for (int kt = 0; kt < 16; ++kt) {
        bf16x8 av = *(const bf16x8*)(Ar + kt * 32);
        bf16x8 bv = *(const bf16x8*)(hp + kt * 32);
        acc = __builtin_amdgcn_mfma_f32_16x16x32_bf16(av, bv, acc, 0, 0, 0);
    }

    // ---- stage into LDS ----
    *(unsigned long long*)&act[t >> 5][(t & 31) * 4] = hv;   // h part
    if (t < 48) { int r = t / 3, d = t - 3 * r; cds[r][d] = cdv; }
#pragma unroll
    for (int r = 0; r < 4; ++r)
        act[q * 4 + r][128 + gw * 16 + m] = (__bf16)acc[r];  // V part
    __syncthreads();

    // ---- layer 1: cols gw*32 + ct*16 + m ----
    bf16x8 af[8];
#pragma unroll
    for (int ch = 0; ch < 8; ++ch)
        af[ch] = *(const bf16x8*)&act[m][q * 8 + 32 * ch];

#pragma unroll
    for (int ct = 0; ct < 2; ++ct) {
        const int c = gw * 32 + ct * 16 + m;
        const float wx = uw0[128 * 256 + c];
        const float wy = uw0[129 * 256 + c];
        const float wz = uw0[130 * 256 + c];
        const float bias = ub0[c];
        f32x4 a1c;
#pragma unroll
        for (int r = 0; r < 4; ++r)
            a1c[r] = bias + cds[q * 4 + r][0] * wx + cds[q * 4 + r][1] * wy
                          + cds[q * 4 + r][2] * wz;
        const __bf16* wp = w0t + (size_t)c * 256 + q * 8;
#pragma unroll
        for (int ch = 0; ch < 8; ++ch) {
            bf16x8 bfr = *(const bf16x8*)(wp + 32 * ch);
            a1c = __builtin_amdgcn_mfma_f32_16x16x32_bf16(af[ch], bfr, a1c, 0, 0, 0);
        }
#pragma unroll
        for (int r = 0; r < 4; ++r)
            u1[q * 4 + r][c] = (__bf16)fmaxf(a1c[r], 0.0f);
    }
    __syncthreads();

    // ---- layer 2: cols gw*16 + m ----
    bf16x8 af2[8];
#pragma unroll
    for (int ch = 0; ch < 8; ++ch)
        af2[ch] = *(const bf16x8*)&u1[m][q * 8 + 32 * ch];
    {
        const int c = gw * 16 + m;
        float bias = ub1[c];
        f32x4 a2c = {bias, bias, bias, bias};
        const __bf16* wp = w1t + (size_t)c * 256 + q * 8;
#pragma unroll
        for (int ch = 0; ch < 8; ++ch) {
            bf16x8 bfr = *(const bf16x8*)(wp + 32 * ch);
            a2c = __builtin_amdgcn_mfma_f32_16x16x32_bf16(af2[ch], bfr, a2c, 0, 0, 0);
        }
        float mx = fmaxf(fmaxf(a2c[0], a2c[1]), fmaxf(a2c[2], a2c[3]));
        mx = fmaxf(mx, 0.0f);
        mx = fmaxf(mx, __shfl_xor(mx, 16, 64));
        mx = fmaxf(mx, __shfl_xor(mx, 32, 64));
        if (l < 16)
            atomicMax((int*)(out + ((size_t)b << 7) + c), __float_as_int(mx));
    }
}

extern "C" void kernel_launch(void* const* d_in, const int* in_sizes, int n_in,
                              void* d_out, int out_size, void* d_ws, size_t ws_size,
                              hipStream_t stream)
{
    const float* coords = (const float*)d_in[0];
    const float* fw0 = (const float*)d_in[1];
    const float* fb0 = (const float*)d_in[2];
    const float* fw1 = (const float*)d_in[3];
    const float* fb1 = (const float*)d_in[4];
    const float* aw0 = (const float*)d_in[5];
    const float* ab0 = (const float*)d_in[6];
    const float* aw1 = (const float*)d_in[7];
    const float* ab1 = (const float*)d_in[8];
    const float* aw2 = (const float*)d_in[9];
    const float* ab2 = (const float*)d_in[10];
    const float* uw0 = (const float*)d_in[11];
    const float* ub0 = (const float*)d_in[12];
    const float* uw1 = (const float*)d_in[13];
    const float* ub1 = (const float*)d_in[14];
    float* out = (float*)d_out;

    // workspace layout
    char* ws = (char*)d_ws;
    __bf16* A    = (__bf16*)(ws);                            // 4 MB
    float*  g    = (float*)(ws + (4u << 20));                // 1 MB
    __bf16* h_t  = (__bf16*)(ws + (5u << 20));               // 1 MB
    __bf16* h_bf = (__bf16*)(ws + (6u << 20));               // 1 MB
    __bf16* w0t  = (__bf16*)(ws + (7u << 20));               // 128 KB
    __bf16* w1t  = (__bf16*)(ws + (7u << 20) + (128u << 10));// 64 KB
    __bf16* aw1p = (__bf16*)(ws + (7u << 20) + (192u << 10));// 8 KB
    float*  eb   = (float*)(ws + (7u << 20) + (200u << 10)); // 256 B
    float*  ew   = (float*)(ws + (7u << 20) + (201u << 10)); // 256 B

    k_stage1<<<4905, 128, 0, stream>>>(coords, fw0, fb0, fw1, fb1, aw0, aw1,
                                       ab1, aw2, uw0, uw1,
                                       h_bf, h_t, g, w0t, w1t, aw1p, eb, ew,
                                       out, out_size);
    k_adj<<<1024, 256, 0, stream>>>(coords, g, aw0, ab0, aw1p, eb, ew, ab2, A);
    k_aggupd<<<256, 512, 0, stream>>>(A, h_t, h_bf, coords, uw0, ub0,
                                      w0t, w1t, ub1, out);
}

// Round 9
// 158.523 us; speedup vs baseline: 1.1543x; 1.1471x over previous
//
#include <hip/hip_runtime.h>
#include <hip/hip_bf16.h>

#define B_ 8
#define N_ 512

typedef __attribute__((ext_vector_type(8))) __bf16 bf16x8;
typedef __attribute__((ext_vector_type(4))) float f32x4;
typedef __attribute__((ext_vector_type(4))) unsigned int u32x4;

// pack two fp32 into bf16x2 by truncation: 1 v_perm_b32
__device__ __forceinline__ unsigned pk_bf16(float hi, float lo) {
    return __builtin_amdgcn_perm(__builtin_bit_cast(unsigned, hi),
                                 __builtin_bit_cast(unsigned, lo), 0x07060302u);
}

// ---------------- stage 1: fused node-MLP | weight-prep | zero-out ----------
// [0,4096)      node MLP (h_bf, h_t)
// [4096,4864)   w0t/w1t transpose->bf16
// [4864,4896)   aw1p fragment pack
// [4896,4904)   zero d_out
// 4904          eb/ew epilogue constants
__global__ __launch_bounds__(128) void k_stage1(
    const float* __restrict__ coords,
    const float* __restrict__ fw0, const float* __restrict__ fb0,
    const float* __restrict__ fw1, const float* __restrict__ fb1,
    const float* __restrict__ aw1,
    const float* __restrict__ ab1, const float* __restrict__ aw2,
    const float* __restrict__ uw0, const float* __restrict__ uw1,
    __bf16* __restrict__ h_bf, __bf16* __restrict__ h_t,
    __bf16* __restrict__ w0t, __bf16* __restrict__ w1t,
    __bf16* __restrict__ aw1p, float* __restrict__ eb, float* __restrict__ ew,
    float* __restrict__ out, int out_size)
{
    const int blk = blockIdx.x;
    const int t = threadIdx.x;

    if (blk < 4096) {
        int row = blk;                 // b*512 + n
        int b = row >> 9;
        int n = row & 511;
        __shared__ float c[3];
        __shared__ float hid[64];
        if (t < 3) c[t] = coords[row * 3 + t];
        __syncthreads();
        if (t < 64) {
            float v = fb0[t];
            v += c[0] * fw0[0 * 64 + t];
            v += c[1] * fw0[1 * 64 + t];
            v += c[2] * fw0[2 * 64 + t];
            hid[t] = fmaxf(v, 0.0f);
        }
        __syncthreads();
        float acc = fb1[t];
#pragma unroll
        for (int k = 0; k < 64; ++k) acc += hid[k] * fw1[k * 128 + t];
        float r = fmaxf(acc, 0.0f);
        h_bf[((size_t)row << 7) + t] = (__bf16)r;
        h_t[(size_t)(b * 128 + t) * 512 + n] = (__bf16)r;
    } else if (blk < 4864) {
        int id = (blk - 4096) * 128 + t;    // 0..98303
        if (id < 65536) {
            int c = id >> 8, k = id & 255;
            int src = (k < 128) ? k : (k + 3);
            w0t[(size_t)c * 256 + k] = (__bf16)uw0[(size_t)src * 256 + c];
        } else {
            int id2 = id - 65536;
            int c = id2 >> 8, k = id2 & 255;
            w1t[(size_t)c * 256 + k] = (__bf16)uw1[(size_t)k * 128 + c];
        }
    } else if (blk < 4896) {
        // aw1p[s*2048 + ct*512 + q*128 + m*8 + j] = aw1[(s*32+q*8+j)*64 + ct*16+m]
        int id = (blk - 4864) * 128 + t;    // 0..4095
        int j = id & 7, m = (id >> 3) & 15, q = (id >> 7) & 3;
        int ct = (id >> 9) & 3, s = (id >> 11) & 1;
        aw1p[id] = (__bf16)aw1[(s * 32 + q * 8 + j) * 64 + ct * 16 + m];
    } else if (blk < 4904) {
        int i = (blk - 4896) * 128 + t;
        if (i < out_size) out[i] = 0.0f;
    } else {
        if (t < 64) {
            int q = t >> 4, ct = (t >> 2) & 3, r = t & 3;
            int ch = ct * 16 + q * 4 + r;
            eb[t] = ab1[ch];
            ew[t] = aw2[ch];
        }
    }
}

// ---------------- adjacency MLP via bf16 MFMA, transposed epilogue ----------
// 2048 blocks x 4 waves: blk -> (b, i-group of 4, j-half). Wave owns one
// i-row and 16 j-tiles (256 pairs). Layer-0 computed from coords directly
// (L1-resident) — no g table. No manual prefetch (keeps VGPR low for TLP).
__global__ __launch_bounds__(256) void k_adj(
    const float* __restrict__ coords,
    const float* __restrict__ aw0, const float* __restrict__ ab0,
    const __bf16* __restrict__ aw1p,
    const float* __restrict__ eb, const float* __restrict__ ew,
    const float* __restrict__ ab2,
    __bf16* __restrict__ A)
{
    const int tid = threadIdx.x;
    const int l = tid & 63;
    const int wave = tid >> 6;
    const int q = l >> 4;
    const int m = l & 15;
    const int b = blockIdx.x >> 8;
    const int half = blockIdx.x & 1;
    const int i = (((blockIdx.x >> 1) & 127) << 2) + wave;

    const float* ci = coords + (size_t)(b * N_ + i) * 3;
    const float ci0 = ci[0], ci1 = ci[1], ci2 = ci[2];

    // layer-0 per-lane constants: offsets o (ci part folded) and cj weights
    f32x4 o0a, o0b, o1a, o1b;
    f32x4 w3a0, w3a1, w3b0, w3b1;
    f32x4 w4a0, w4a1, w4b0, w4b1;
    f32x4 w5a0, w5a1, w5b0, w5b1;
    {
        int base = q * 8;
        f32x4 bb0 = *(const f32x4*)(ab0 + base);
        f32x4 bb1 = *(const f32x4*)(ab0 + base + 4);
        f32x4 wa0 = *(const f32x4*)(aw0 + base);
        f32x4 wa1 = *(const f32x4*)(aw0 + base + 4);
        f32x4 wb0 = *(const f32x4*)(aw0 + 64 + base);
        f32x4 wb1 = *(const f32x4*)(aw0 + 64 + base + 4);
        f32x4 wc0 = *(const f32x4*)(aw0 + 128 + base);
        f32x4 wc1 = *(const f32x4*)(aw0 + 128 + base + 4);
        o0a = bb0 + ci0 * wa0 + ci1 * wb0 + ci2 * wc0;
        o0b = bb1 + ci0 * wa1 + ci1 * wb1 + ci2 * wc1;
        w3a0 = *(const f32x4*)(aw0 + 192 + base);
        w3a1 = *(const f32x4*)(aw0 + 192 + base + 4);
        w4a0 = *(const f32x4*)(aw0 + 256 + base);
        w4a1 = *(const f32x4*)(aw0 + 256 + base + 4);
        w5a0 = *(const f32x4*)(aw0 + 320 + base);
        w5a1 = *(const f32x4*)(aw0 + 320 + base + 4);
        base = 32 + q * 8;
        bb0 = *(const f32x4*)(ab0 + base);
        bb1 = *(const f32x4*)(ab0 + base + 4);
        wa0 = *(const f32x4*)(aw0 + base);
        wa1 = *(const f32x4*)(aw0 + base + 4);
        wb0 = *(const f32x4*)(aw0 + 64 + base);
        wb1 = *(const f32x4*)(aw0 + 64 + base + 4);
        wc0 = *(const f32x4*)(aw0 + 128 + base);
        wc1 = *(const f32x4*)(aw0 + 128 + base + 4);
        o1a = bb0 + ci0 * wa0 + ci1 * wb0 + ci2 * wc0;
        o1b = bb1 + ci0 * wa1 + ci1 * wb1 + ci2 * wc1;
        w3b0 = *(const f32x4*)(aw0 + 192 + base);
        w3b1 = *(const f32x4*)(aw0 + 192 + base + 4);
        w4b0 = *(const f32x4*)(aw0 + 256 + base);
        w4b1 = *(const f32x4*)(aw0 + 256 + base + 4);
        w5b0 = *(const f32x4*)(aw0 + 320 + base);
        w5b1 = *(const f32x4*)(aw0 + 320 + base + 4);
    }

    // aw1 fragments: single 16B load each
    bf16x8 bfr[2][4];
#pragma unroll
    for (int s = 0; s < 2; ++s)
#pragma unroll
        for (int ct = 0; ct < 4; ++ct)
            bfr[s][ct] = *(const bf16x8*)(aw1p + s * 2048 + ct * 512 + q * 128 + m * 8);

    f32x4 ab1q[4], ewq[4];
#pragma unroll
    for (int ct = 0; ct < 4; ++ct) {
        ab1q[ct] = *(const f32x4*)(eb + q * 16 + ct * 4);
        ewq[ct] = *(const f32x4*)(ew + q * 16 + ct * 4);
    }
    const float ab2s = ab2[0];

    __bf16* Arow = A + ((size_t)(b * N_ + i) << 9) + half * 256;
    const float* cjbase = coords + (size_t)(b * N_ + half * 256 + m) * 3;

#pragma unroll 1
    for (int t = 0; t < 16; ++t) {
        const float* cj = cjbase + t * 48;     // 16 pairs * 3 floats
        float d0 = cj[0], d1 = cj[1], d2 = cj[2];

        // layer 0: relu(o + cj . w345), pack to bf16 via v_perm truncation
        f32x4 v0, v1, v2, v3;
#pragma unroll
        for (int j = 0; j < 4; ++j) {
            v0[j] = fmaxf(o0a[j] + d0 * w3a0[j] + d1 * w4a0[j] + d2 * w5a0[j], 0.0f);
            v1[j] = fmaxf(o0b[j] + d0 * w3a1[j] + d1 * w4a1[j] + d2 * w5a1[j], 0.0f);
            v2[j] = fmaxf(o1a[j] + d0 * w3b0[j] + d1 * w4b0[j] + d2 * w5b0[j], 0.0f);
            v3[j] = fmaxf(o1b[j] + d0 * w3b1[j] + d1 * w4b1[j] + d2 * w5b1[j], 0.0f);
        }
        u32x4 pa, pb;
        pa[0] = pk_bf16(v0[1], v0[0]); pa[1] = pk_bf16(v0[3], v0[2]);
        pa[2] = pk_bf16(v1[1], v1[0]); pa[3] = pk_bf16(v1[3], v1[2]);
        pb[0] = pk_bf16(v2[1], v2[0]); pb[1] = pk_bf16(v2[3], v2[2]);
        pb[2] = pk_bf16(v3[1], v3[0]); pb[3] = pk_bf16(v3[3], v3[2]);
        bf16x8 a0 = __builtin_bit_cast(bf16x8, pa);
        bf16x8 a1 = __builtin_bit_cast(bf16x8, pb);

        // layer 1 transposed MFMA; ab1 folded into C-init
        float p0, p1, p2, p3;
        {
            f32x4 c0v = ab1q[0];
            c0v = __builtin_amdgcn_mfma_f32_16x16x32_bf16(bfr[0][0], a0, c0v, 0, 0, 0);
            c0v = __builtin_amdgcn_mfma_f32_16x16x32_bf16(bfr[1][0], a1, c0v, 0, 0, 0);
            f32x4 c1v = ab1q[1];
            c1v = __builtin_amdgcn_mfma_f32_16x16x32_bf16(bfr[0][1], a0, c1v, 0, 0, 0);
            c1v = __builtin_amdgcn_mfma_f32_16x16x32_bf16(bfr[1][1], a1, c1v, 0, 0, 0);
            f32x4 c2v = ab1q[2];
            c2v = __builtin_amdgcn_mfma_f32_16x16x32_bf16(bfr[0][2], a0, c2v, 0, 0, 0);
            c2v = __builtin_amdgcn_mfma_f32_16x16x32_bf16(bfr[1][2], a1, c2v, 0, 0, 0);
            f32x4 c3v = ab1q[3];
            c3v = __builtin_amdgcn_mfma_f32_16x16x32_bf16(bfr[0][3], a0, c3v, 0, 0, 0);
            c3v = __builtin_amdgcn_mfma_f32_16x16x32_bf16(bfr[1][3], a1, c3v, 0, 0, 0);
            p0 = fmaxf(c0v[0], 0.f) * ewq[0][0] + fmaxf(c0v[1], 0.f) * ewq[0][1]
               + fmaxf(c0v[2], 0.f) * ewq[0][2] + fmaxf(c0v[3], 0.f) * ewq[0][3];
            p1 = fmaxf(c1v[0], 0.f) * ewq[1][0] + fmaxf(c1v[1], 0.f) * ewq[1][1]
               + fmaxf(c1v[2], 0.f) * ewq[1][2] + fmaxf(c1v[3], 0.f) * ewq[1][3];
            p2 = fmaxf(c2v[0], 0.f) * ewq[2][0] + fmaxf(c2v[1], 0.f) * ewq[2][1]
               + fmaxf(c2v[2], 0.f) * ewq[2][2] + fmaxf(c2v[3], 0.f) * ewq[2][3];
            p3 = fmaxf(c3v[0], 0.f) * ewq[3][0] + fmaxf(c3v[1], 0.f) * ewq[3][1]
               + fmaxf(c3v[2], 0.f) * ewq[3][2] + fmaxf(c3v[3], 0.f) * ewq[3][3];
        }
        float p = (p0 + p1) + (p2 + p3);
        p += __shfl_xor(p, 16, 64);
        p += __shfl_xor(p, 32, 64);
        if (l < 16) Arow[(t << 4) + l] = (__bf16)fmaxf(ab2s + p, 0.0f);
    }
}

// ---------------- fused  V = A@h (MFMA)  +  update MLP  +  max pool ---------
// 256 blocks x 512 thr (8 waves). Wave gw computes V n-tile gw (16 rows x 16
// cols, K=512) straight into LDS act; then 259->256->128 MLP via MFMA.
// row0 is the GLOBAL row — A is indexed by global row directly.
__global__ __launch_bounds__(512) void k_aggupd(
    const __bf16* __restrict__ A, const __bf16* __restrict__ h_t,
    const __bf16* __restrict__ h_bf, const float* __restrict__ coords,
    const float* __restrict__ uw0, const float* __restrict__ ub0,
    const __bf16* __restrict__ w0t, const __bf16* __restrict__ w1t,
    const float* __restrict__ ub1,
    float* __restrict__ out)
{
    const int t = threadIdx.x;
    const int gw = t >> 6;           // wave 0..7
    const int l = t & 63;
    const int q = l >> 4;
    const int m = l & 15;
    const int row0 = blockIdx.x << 4;   // 16 GLOBAL rows, same b
    const int b = row0 >> 9;

    __shared__ __align__(16) __bf16 act[16][256];  // [row][k], k=[h|V]
    __shared__ __align__(16) __bf16 u1[16][256];
    __shared__ float cds[16][4];

    // issue staging loads early
    unsigned long long hv = *(const unsigned long long*)
        (h_bf + ((size_t)(row0 + (t >> 5)) << 7) + (t & 31) * 4);
    float cdv = 0.0f;
    if (t < 48) cdv = coords[(size_t)row0 * 3 + t];

    // ---- aggregate: V tile via MFMA (A indexed by global row!) ----
    const __bf16* Ar = A + (size_t)(row0 + m) * 512 + q * 8;
    const __bf16* hp = h_t + ((size_t)b << 16) + (size_t)(gw * 16 + m) * 512 + q * 8;
    f32x4 acc = {0.f, 0.f, 0.f, 0.f};
#pragma unroll 4
    for (int kt = 0; kt < 16; ++kt) {
        bf16x8 av = *(const bf16x8*)(Ar + kt * 32);
        bf16x8 bv = *(const bf16x8*)(hp + kt * 32);
        acc = __builtin_amdgcn_mfma_f32_16x16x32_bf16(av, bv, acc, 0, 0, 0);
    }

    // ---- stage into LDS ----
    *(unsigned long long*)&act[t >> 5][(t & 31) * 4] = hv;   // h part
    if (t < 48) { int r = t / 3, d = t - 3 * r; cds[r][d] = cdv; }
#pragma unroll
    for (int r = 0; r < 4; ++r)
        act[q * 4 + r][128 + gw * 16 + m] = (__bf16)acc[r];  // V part
    __syncthreads();

    // ---- layer 1: cols gw*32 + ct*16 + m ----
    bf16x8 af[8];
#pragma unroll
    for (int ch = 0; ch < 8; ++ch)
        af[ch] = *(const bf16x8*)&act[m][q * 8 + 32 * ch];

#pragma unroll
    for (int ct = 0; ct < 2; ++ct) {
        const int c = gw * 32 + ct * 16 + m;
        const float wx = uw0[128 * 256 + c];
        const float wy = uw0[129 * 256 + c];
        const float wz = uw0[130 * 256 + c];
        const float bias = ub0[c];
        f32x4 a1c;
#pragma unroll
        for (int r = 0; r < 4; ++r)
            a1c[r] = bias + cds[q * 4 + r][0] * wx + cds[q * 4 + r][1] * wy
                          + cds[q * 4 + r][2] * wz;
        const __bf16* wp = w0t + (size_t)c * 256 + q * 8;
#pragma unroll
        for (int ch = 0; ch < 8; ++ch) {
            bf16x8 bfr = *(const bf16x8*)(wp + 32 * ch);
            a1c = __builtin_amdgcn_mfma_f32_16x16x32_bf16(af[ch], bfr, a1c, 0, 0, 0);
        }
#pragma unroll
        for (int r = 0; r < 4; ++r)
            u1[q * 4 + r][c] = (__bf16)fmaxf(a1c[r], 0.0f);
    }
    __syncthreads();

    // ---- layer 2: cols gw*16 + m ----
    bf16x8 af2[8];
#pragma unroll
    for (int ch = 0; ch < 8; ++ch)
        af2[ch] = *(const bf16x8*)&u1[m][q * 8 + 32 * ch];
    {
        const int c = gw * 16 + m;
        float bias = ub1[c];
        f32x4 a2c = {bias, bias, bias, bias};
        const __bf16* wp = w1t + (size_t)c * 256 + q * 8;
#pragma unroll
        for (int ch = 0; ch < 8; ++ch) {
            bf16x8 bfr = *(const bf16x8*)(wp + 32 * ch);
            a2c = __builtin_amdgcn_mfma_f32_16x16x32_bf16(af2[ch], bfr, a2c, 0, 0, 0);
        }
        float mx = fmaxf(fmaxf(a2c[0], a2c[1]), fmaxf(a2c[2], a2c[3]));
        mx = fmaxf(mx, 0.0f);
        mx = fmaxf(mx, __shfl_xor(mx, 16, 64));
        mx = fmaxf(mx, __shfl_xor(mx, 32, 64));
        if (l < 16)
            atomicMax((int*)(out + ((size_t)b << 7) + c), __float_as_int(mx));
    }
}

extern "C" void kernel_launch(void* const* d_in, const int* in_sizes, int n_in,
                              void* d_out, int out_size, void* d_ws, size_t ws_size,
                              hipStream_t stream)
{
    const float* coords = (const float*)d_in[0];
    const float* fw0 = (const float*)d_in[1];
    const float* fb0 = (const float*)d_in[2];
    const float* fw1 = (const float*)d_in[3];
    const float* fb1 = (const float*)d_in[4];
    const float* aw0 = (const float*)d_in[5];
    const float* ab0 = (const float*)d_in[6];
    const float* aw1 = (const float*)d_in[7];
    const float* ab1 = (const float*)d_in[8];
    const float* aw2 = (const float*)d_in[9];
    const float* ab2 = (const float*)d_in[10];
    const float* uw0 = (const float*)d_in[11];
    const float* ub0 = (const float*)d_in[12];
    const float* uw1 = (const float*)d_in[13];
    const float* ub1 = (const float*)d_in[14];
    float* out = (float*)d_out;

    // workspace layout
    char* ws = (char*)d_ws;
    __bf16* A    = (__bf16*)(ws);                            // 4 MB
    __bf16* h_t  = (__bf16*)(ws + (4u << 20));               // 1 MB
    __bf16* h_bf = (__bf16*)(ws + (5u << 20));               // 1 MB
    __bf16* w0t  = (__bf16*)(ws + (6u << 20));               // 128 KB
    __bf16* w1t  = (__bf16*)(ws + (6u << 20) + (128u << 10));// 64 KB
    __bf16* aw1p = (__bf16*)(ws + (6u << 20) + (192u << 10));// 8 KB
    float*  eb   = (float*)(ws + (6u << 20) + (200u << 10)); // 256 B
    float*  ew   = (float*)(ws + (6u << 20) + (201u << 10)); // 256 B

    k_stage1<<<4905, 128, 0, stream>>>(coords, fw0, fb0, fw1, fb1, aw1,
                                       ab1, aw2, uw0, uw1,
                                       h_bf, h_t, w0t, w1t, aw1p, eb, ew,
                                       out, out_size);
    k_adj<<<2048, 256, 0, stream>>>(coords, aw0, ab0, aw1p, eb, ew, ab2, A);
    k_aggupd<<<256, 512, 0, stream>>>(A, h_t, h_bf, coords, uw0, ub0,
                                      w0t, w1t, ub1, out);
}

// Round 10
// 156.452 us; speedup vs baseline: 1.1695x; 1.0132x over previous
//
#include <hip/hip_runtime.h>
#include <hip/hip_bf16.h>

#define B_ 8
#define N_ 512

typedef __attribute__((ext_vector_type(8))) __bf16 bf16x8;
typedef __attribute__((ext_vector_type(4))) float f32x4;
typedef __attribute__((ext_vector_type(4))) unsigned int u32x4;

// pack two fp32 into bf16x2 by truncation: 1 v_perm_b32
__device__ __forceinline__ unsigned pk_bf16(float hi, float lo) {
    return __builtin_amdgcn_perm(__builtin_bit_cast(unsigned, hi),
                                 __builtin_bit_cast(unsigned, lo), 0x07060302u);
}

// ---------------- stage 1: fused node-MLP | weight-prep | zero-out ----------
// [0,512)      node MLP, 8 rows/block: h_bf coalesced, h_t via 16B stores
// [512,1024)   w0t transpose (coalesced reads, scattered writes)
// [1024,1280)  w1t transpose
// [1280,1312)  aw1p fragment pack
// [1312,1320)  zero d_out
// 1320         eb/ew epilogue constants
__global__ __launch_bounds__(128) void k_stage1(
    const float* __restrict__ coords,
    const float* __restrict__ fw0, const float* __restrict__ fb0,
    const float* __restrict__ fw1, const float* __restrict__ fb1,
    const float* __restrict__ aw1,
    const float* __restrict__ ab1, const float* __restrict__ aw2,
    const float* __restrict__ uw0, const float* __restrict__ uw1,
    __bf16* __restrict__ h_bf, __bf16* __restrict__ h_t,
    __bf16* __restrict__ w0t, __bf16* __restrict__ w1t,
    __bf16* __restrict__ aw1p, float* __restrict__ eb, float* __restrict__ ew,
    float* __restrict__ out, int out_size)
{
    const int blk = blockIdx.x;
    const int t = threadIdx.x;

    if (blk < 512) {
        // ---- node MLP: rows row0..row0+7 (same batch; 512 % 8 == 0) ----
        const int row0 = blk << 3;
        const int b = row0 >> 9;
        const int n0 = row0 & 511;
        __shared__ float cds[8][4];
        __shared__ float hid[8][64];
        if (t < 24) {
            int r = t / 3, d = t - 3 * r;
            cds[r][d] = coords[(size_t)(row0 + r) * 3 + d];
        }
        __syncthreads();
        // hid for 8 rows: 128 thr = 2 rows at a time
        {
            int ch = t & 63;
            int rh = t >> 6;
#pragma unroll
            for (int rr = 0; rr < 4; ++rr) {
                int r = rr * 2 + rh;
                float v = fb0[ch];
                v += cds[r][0] * fw0[0 * 64 + ch];
                v += cds[r][1] * fw0[1 * 64 + ch];
                v += cds[r][2] * fw0[2 * 64 + ch];
                hid[r][ch] = fmaxf(v, 0.0f);
            }
        }
        __syncthreads();
        // layer 2: thread t = channel, 8 rows
        float hv[8];
        {
            float bias = fb1[t];
#pragma unroll
            for (int r = 0; r < 8; ++r) hv[r] = bias;
#pragma unroll 4
            for (int k = 0; k < 64; ++k) {
                float w = fw1[k * 128 + t];
#pragma unroll
                for (int r = 0; r < 8; ++r) hv[r] += hid[r][k] * w;
            }
#pragma unroll
            for (int r = 0; r < 8; ++r) hv[r] = fmaxf(hv[r], 0.0f);
        }
        // h_bf: coalesced 2B stores per row
#pragma unroll
        for (int r = 0; r < 8; ++r)
            h_bf[((size_t)(row0 + r) << 7) + t] = (__bf16)hv[r];
        // h_t: thread t holds channel t for 8 consecutive n -> one 16B store
        u32x4 pk;
        pk[0] = pk_bf16(hv[1], hv[0]);
        pk[1] = pk_bf16(hv[3], hv[2]);
        pk[2] = pk_bf16(hv[5], hv[4]);
        pk[3] = pk_bf16(hv[7], hv[6]);
        *(u32x4*)(h_t + (size_t)(b * 128 + t) * 512 + n0) = pk;
    } else if (blk < 1024) {
        // ---- w0t[c][k] = uw0[perm(k)][c]; coalesced read ----
        int blk2 = blk - 512;
        int k = blk2 >> 1;
        int c = ((blk2 & 1) << 7) + t;
        int src = (k < 128) ? k : (k + 3);
        w0t[(size_t)c * 256 + k] = (__bf16)uw0[(size_t)src * 256 + c];
    } else if (blk < 1280) {
        // ---- w1t[c][k] = uw1[k][c]; coalesced read ----
        int k = blk - 1024;
        int c = t;
        w1t[(size_t)c * 256 + k] = (__bf16)uw1[(size_t)k * 128 + c];
    } else if (blk < 1312) {
        // aw1p[s*2048 + ct*512 + q*128 + m*8 + j] = aw1[(s*32+q*8+j)*64 + ct*16+m]
        int id = (blk - 1280) * 128 + t;    // 0..4095
        int j = id & 7, m = (id >> 3) & 15, q = (id >> 7) & 3;
        int ct = (id >> 9) & 3, s = (id >> 11) & 1;
        aw1p[id] = (__bf16)aw1[(s * 32 + q * 8 + j) * 64 + ct * 16 + m];
    } else if (blk < 1320) {
        int i = (blk - 1312) * 128 + t;
        if (i < out_size) out[i] = 0.0f;
    } else {
        if (t < 64) {
            int q = t >> 4, ct = (t >> 2) & 3, r = t & 3;
            int ch = ct * 16 + q * 4 + r;
            eb[t] = ab1[ch];
            ew[t] = aw2[ch];
        }
    }
}

// ---------------- adjacency MLP via bf16 MFMA (unchanged from R9) -----------
__global__ __launch_bounds__(256) void k_adj(
    const float* __restrict__ coords,
    const float* __restrict__ aw0, const float* __restrict__ ab0,
    const __bf16* __restrict__ aw1p,
    const float* __restrict__ eb, const float* __restrict__ ew,
    const float* __restrict__ ab2,
    __bf16* __restrict__ A)
{
    const int tid = threadIdx.x;
    const int l = tid & 63;
    const int wave = tid >> 6;
    const int q = l >> 4;
    const int m = l & 15;
    const int b = blockIdx.x >> 8;
    const int half = blockIdx.x & 1;
    const int i = (((blockIdx.x >> 1) & 127) << 2) + wave;

    const float* ci = coords + (size_t)(b * N_ + i) * 3;
    const float ci0 = ci[0], ci1 = ci[1], ci2 = ci[2];

    f32x4 o0a, o0b, o1a, o1b;
    f32x4 w3a0, w3a1, w3b0, w3b1;
    f32x4 w4a0, w4a1, w4b0, w4b1;
    f32x4 w5a0, w5a1, w5b0, w5b1;
    {
        int base = q * 8;
        f32x4 bb0 = *(const f32x4*)(ab0 + base);
        f32x4 bb1 = *(const f32x4*)(ab0 + base + 4);
        f32x4 wa0 = *(const f32x4*)(aw0 + base);
        f32x4 wa1 = *(const f32x4*)(aw0 + base + 4);
        f32x4 wb0 = *(const f32x4*)(aw0 + 64 + base);
        f32x4 wb1 = *(const f32x4*)(aw0 + 64 + base + 4);
        f32x4 wc0 = *(const f32x4*)(aw0 + 128 + base);
        f32x4 wc1 = *(const f32x4*)(aw0 + 128 + base + 4);
        o0a = bb0 + ci0 * wa0 + ci1 * wb0 + ci2 * wc0;
        o0b = bb1 + ci0 * wa1 + ci1 * wb1 + ci2 * wc1;
        w3a0 = *(const f32x4*)(aw0 + 192 + base);
        w3a1 = *(const f32x4*)(aw0 + 192 + base + 4);
        w4a0 = *(const f32x4*)(aw0 + 256 + base);
        w4a1 = *(const f32x4*)(aw0 + 256 + base + 4);
        w5a0 = *(const f32x4*)(aw0 + 320 + base);
        w5a1 = *(const f32x4*)(aw0 + 320 + base + 4);
        base = 32 + q * 8;
        bb0 = *(const f32x4*)(ab0 + base);
        bb1 = *(const f32x4*)(ab0 + base + 4);
        wa0 = *(const f32x4*)(aw0 + base);
        wa1 = *(const f32x4*)(aw0 + base + 4);
        wb0 = *(const f32x4*)(aw0 + 64 + base);
        wb1 = *(const f32x4*)(aw0 + 64 + base + 4);
        wc0 = *(const f32x4*)(aw0 + 128 + base);
        wc1 = *(const f32x4*)(aw0 + 128 + base + 4);
        o1a = bb0 + ci0 * wa0 + ci1 * wb0 + ci2 * wc0;
        o1b = bb1 + ci0 * wa1 + ci1 * wb1 + ci2 * wc1;
        w3b0 = *(const f32x4*)(aw0 + 192 + base);
        w3b1 = *(const f32x4*)(aw0 + 192 + base + 4);
        w4b0 = *(const f32x4*)(aw0 + 256 + base);
        w4b1 = *(const f32x4*)(aw0 + 256 + base + 4);
        w5b0 = *(const f32x4*)(aw0 + 320 + base);
        w5b1 = *(const f32x4*)(aw0 + 320 + base + 4);
    }

    bf16x8 bfr[2][4];
#pragma unroll
    for (int s = 0; s < 2; ++s)
#pragma unroll
        for (int ct = 0; ct < 4; ++ct)
            bfr[s][ct] = *(const bf16x8*)(aw1p + s * 2048 + ct * 512 + q * 128 + m * 8);

    f32x4 ab1q[4], ewq[4];
#pragma unroll
    for (int ct = 0; ct < 4; ++ct) {
        ab1q[ct] = *(const f32x4*)(eb + q * 16 + ct * 4);
        ewq[ct] = *(const f32x4*)(ew + q * 16 + ct * 4);
    }
    const float ab2s = ab2[0];

    __bf16* Arow = A + ((size_t)(b * N_ + i) << 9) + half * 256;
    const float* cjbase = coords + (size_t)(b * N_ + half * 256 + m) * 3;

#pragma unroll 1
    for (int t = 0; t < 16; ++t) {
        const float* cj = cjbase + t * 48;
        float d0 = cj[0], d1 = cj[1], d2 = cj[2];

        f32x4 v0, v1, v2, v3;
#pragma unroll
        for (int j = 0; j < 4; ++j) {
            v0[j] = fmaxf(o0a[j] + d0 * w3a0[j] + d1 * w4a0[j] + d2 * w5a0[j], 0.0f);
            v1[j] = fmaxf(o0b[j] + d0 * w3a1[j] + d1 * w4a1[j] + d2 * w5a1[j], 0.0f);
            v2[j] = fmaxf(o1a[j] + d0 * w3b0[j] + d1 * w4b0[j] + d2 * w5b0[j], 0.0f);
            v3[j] = fmaxf(o1b[j] + d0 * w3b1[j] + d1 * w4b1[j] + d2 * w5b1[j], 0.0f);
        }
        u32x4 pa, pb;
        pa[0] = pk_bf16(v0[1], v0[0]); pa[1] = pk_bf16(v0[3], v0[2]);
        pa[2] = pk_bf16(v1[1], v1[0]); pa[3] = pk_bf16(v1[3], v1[2]);
        pb[0] = pk_bf16(v2[1], v2[0]); pb[1] = pk_bf16(v2[3], v2[2]);
        pb[2] = pk_bf16(v3[1], v3[0]); pb[3] = pk_bf16(v3[3], v3[2]);
        bf16x8 a0 = __builtin_bit_cast(bf16x8, pa);
        bf16x8 a1 = __builtin_bit_cast(bf16x8, pb);

        float p0, p1, p2, p3;
        {
            f32x4 c0v = ab1q[0];
            c0v = __builtin_amdgcn_mfma_f32_16x16x32_bf16(bfr[0][0], a0, c0v, 0, 0, 0);
            c0v = __builtin_amdgcn_mfma_f32_16x16x32_bf16(bfr[1][0], a1, c0v, 0, 0, 0);
            f32x4 c1v = ab1q[1];
            c1v = __builtin_amdgcn_mfma_f32_16x16x32_bf16(bfr[0][1], a0, c1v, 0, 0, 0);
            c1v = __builtin_amdgcn_mfma_f32_16x16x32_bf16(bfr[1][1], a1, c1v, 0, 0, 0);
            f32x4 c2v = ab1q[2];
            c2v = __builtin_amdgcn_mfma_f32_16x16x32_bf16(bfr[0][2], a0, c2v, 0, 0, 0);
            c2v = __builtin_amdgcn_mfma_f32_16x16x32_bf16(bfr[1][2], a1, c2v, 0, 0, 0);
            f32x4 c3v = ab1q[3];
            c3v = __builtin_amdgcn_mfma_f32_16x16x32_bf16(bfr[0][3], a0, c3v, 0, 0, 0);
            c3v = __builtin_amdgcn_mfma_f32_16x16x32_bf16(bfr[1][3], a1, c3v, 0, 0, 0);
            p0 = fmaxf(c0v[0], 0.f) * ewq[0][0] + fmaxf(c0v[1], 0.f) * ewq[0][1]
               + fmaxf(c0v[2], 0.f) * ewq[0][2] + fmaxf(c0v[3], 0.f) * ewq[0][3];
            p1 = fmaxf(c1v[0], 0.f) * ewq[1][0] + fmaxf(c1v[1], 0.f) * ewq[1][1]
               + fmaxf(c1v[2], 0.f) * ewq[1][2] + fmaxf(c1v[3], 0.f) * ewq[1][3];
            p2 = fmaxf(c2v[0], 0.f) * ewq[2][0] + fmaxf(c2v[1], 0.f) * ewq[2][1]
               + fmaxf(c2v[2], 0.f) * ewq[2][2] + fmaxf(c2v[3], 0.f) * ewq[2][3];
            p3 = fmaxf(c3v[0], 0.f) * ewq[3][0] + fmaxf(c3v[1], 0.f) * ewq[3][1]
               + fmaxf(c3v[2], 0.f) * ewq[3][2] + fmaxf(c3v[3], 0.f) * ewq[3][3];
        }
        float p = (p0 + p1) + (p2 + p3);
        p += __shfl_xor(p, 16, 64);
        p += __shfl_xor(p, 32, 64);
        if (l < 16) Arow[(t << 4) + l] = (__bf16)fmaxf(ab2s + p, 0.0f);
    }
}

// ---------------- fused  V = A@h (MFMA, K-split x2)  +  update MLP ----------
// 256 blocks x 1024 thr (16 waves, 4 waves/SIMD). Aggregate: wave (gw, ks)
// computes n-tile gw over K-half ks; partials summed in LDS. Layer 1: 16
// col-tiles, 1/wave. Layer 2: 8 tiles on waves 0..7.
__global__ __launch_bounds__(1024) void k_aggupd(
    const __bf16* __restrict__ A, const __bf16* __restrict__ h_t,
    const __bf16* __restrict__ h_bf, const float* __restrict__ coords,
    const float* __restrict__ uw0, const float* __restrict__ ub0,
    const __bf16* __restrict__ w0t, const __bf16* __restrict__ w1t,
    const float* __restrict__ ub1,
    float* __restrict__ out)
{
    const int t = threadIdx.x;
    const int w = t >> 6;            // wave 0..15
    const int gw = w & 7;            // n-tile
    const int ks = w >> 3;           // K-half
    const int l = t & 63;
    const int q = l >> 4;
    const int m = l & 15;
    const int row0 = blockIdx.x << 4;   // 16 GLOBAL rows, same b
    const int b = row0 >> 9;

    __shared__ __align__(16) __bf16 act[16][256];  // [row][k], k=[h|V]
    __shared__ __align__(16) __bf16 u1[16][256];
    __shared__ float vp[2][16][128];
    __shared__ float cds[16][4];

    // stage h part of act: 1024 thr x 4B covers 16x128 bf16
    {
        unsigned hv = *(const unsigned*)(h_bf + ((size_t)row0 << 7) + t * 2);
        *(unsigned*)&act[(t * 2) >> 7][(t * 2) & 127] = hv;
    }
    if (t < 48) {
        int r = t / 3, d = t - 3 * r;
        cds[r][d] = coords[(size_t)row0 * 3 + t];
    }

    // ---- aggregate: V n-tile gw, K-half ks (A indexed by global row) ----
    const __bf16* Ar = A + (size_t)(row0 + m) * 512 + ks * 256 + q * 8;
    const __bf16* hp = h_t + ((size_t)b << 16) + (size_t)(gw * 16 + m) * 512
                       + ks * 256 + q * 8;
    f32x4 acc = {0.f, 0.f, 0.f, 0.f};
#pragma unroll 4
    for (int kt = 0; kt < 8; ++kt) {
        bf16x8 av = *(const bf16x8*)(Ar + kt * 32);
        bf16x8 bv = *(const bf16x8*)(hp + kt * 32);
        acc = __builtin_amdgcn_mfma_f32_16x16x32_bf16(av, bv, acc, 0, 0, 0);
    }
#pragma unroll
    for (int r = 0; r < 4; ++r)
        vp[ks][q * 4 + r][gw * 16 + m] = acc[r];
    __syncthreads();

    // combine K-halves -> act V part (1024 thr x 2 values)
#pragma unroll
    for (int it = 0; it < 2; ++it) {
        int idx = t + it * 1024;
        int row = idx >> 7, ch = idx & 127;
        act[row][128 + ch] = (__bf16)(vp[0][row][ch] + vp[1][row][ch]);
    }
    __syncthreads();

    // ---- layer 1: col c = w*16 + m (16 waves cover 256 cols) ----
    bf16x8 af[8];
#pragma unroll
    for (int ch = 0; ch < 8; ++ch)
        af[ch] = *(const bf16x8*)&act[m][q * 8 + 32 * ch];
    {
        const int c = w * 16 + m;
        const float wx = uw0[128 * 256 + c];
        const float wy = uw0[129 * 256 + c];
        const float wz = uw0[130 * 256 + c];
        const float bias = ub0[c];
        f32x4 a1c;
#pragma unroll
        for (int r = 0; r < 4; ++r)
            a1c[r] = bias + cds[q * 4 + r][0] * wx + cds[q * 4 + r][1] * wy
                          + cds[q * 4 + r][2] * wz;
        const __bf16* wp = w0t + (size_t)c * 256 + q * 8;
#pragma unroll
        for (int ch = 0; ch < 8; ++ch) {
            bf16x8 bfr = *(const bf16x8*)(wp + 32 * ch);
            a1c = __builtin_amdgcn_mfma_f32_16x16x32_bf16(af[ch], bfr, a1c, 0, 0, 0);
        }
#pragma unroll
        for (int r = 0; r < 4; ++r)
            u1[q * 4 + r][c] = (__bf16)fmaxf(a1c[r], 0.0f);
    }
    __syncthreads();

    // ---- layer 2: cols w*16 + m on waves 0..7 ----
    if (w < 8) {
        bf16x8 af2[8];
#pragma unroll
        for (int ch = 0; ch < 8; ++ch)
            af2[ch] = *(const bf16x8*)&u1[m][q * 8 + 32 * ch];
        const int c = w * 16 + m;
        float bias = ub1[c];
        f32x4 a2c = {bias, bias, bias, bias};
        const __bf16* wp = w1t + (size_t)c * 256 + q * 8;
#pragma unroll
        for (int ch = 0; ch < 8; ++ch) {
            bf16x8 bfr = *(const bf16x8*)(wp + 32 * ch);
            a2c = __builtin_amdgcn_mfma_f32_16x16x32_bf16(af2[ch], bfr, a2c, 0, 0, 0);
        }
        float mx = fmaxf(fmaxf(a2c[0], a2c[1]), fmaxf(a2c[2], a2c[3]));
        mx = fmaxf(mx, 0.0f);
        mx = fmaxf(mx, __shfl_xor(mx, 16, 64));
        mx = fmaxf(mx, __shfl_xor(mx, 32, 64));
        if (l < 16)
            atomicMax((int*)(out + ((size_t)b << 7) + c), __float_as_int(mx));
    }
}

extern "C" void kernel_launch(void* const* d_in, const int* in_sizes, int n_in,
                              void* d_out, int out_size, void* d_ws, size_t ws_size,
                              hipStream_t stream)
{
    const float* coords = (const float*)d_in[0];
    const float* fw0 = (const float*)d_in[1];
    const float* fb0 = (const float*)d_in[2];
    const float* fw1 = (const float*)d_in[3];
    const float* fb1 = (const float*)d_in[4];
    const float* aw0 = (const float*)d_in[5];
    const float* ab0 = (const float*)d_in[6];
    const float* aw1 = (const float*)d_in[7];
    const float* ab1 = (const float*)d_in[8];
    const float* aw2 = (const float*)d_in[9];
    const float* ab2 = (const float*)d_in[10];
    const float* uw0 = (const float*)d_in[11];
    const float* ub0 = (const float*)d_in[12];
    const float* uw1 = (const float*)d_in[13];
    const float* ub1 = (const float*)d_in[14];
    float* out = (float*)d_out;

    // workspace layout
    char* ws = (char*)d_ws;
    __bf16* A    = (__bf16*)(ws);                            // 4 MB
    __bf16* h_t  = (__bf16*)(ws + (4u << 20));               // 1 MB
    __bf16* h_bf = (__bf16*)(ws + (5u << 20));               // 1 MB
    __bf16* w0t  = (__bf16*)(ws + (6u << 20));               // 128 KB
    __bf16* w1t  = (__bf16*)(ws + (6u << 20) + (128u << 10));// 64 KB
    __bf16* aw1p = (__bf16*)(ws + (6u << 20) + (192u << 10));// 8 KB
    float*  eb   = (float*)(ws + (6u << 20) + (200u << 10)); // 256 B
    float*  ew   = (float*)(ws + (6u << 20) + (201u << 10)); // 256 B

    k_stage1<<<1321, 128, 0, stream>>>(coords, fw0, fb0, fw1, fb1, aw1,
                                       ab1, aw2, uw0, uw1,
                                       h_bf, h_t, w0t, w1t, aw1p, eb, ew,
                                       out, out_size);
    k_adj<<<2048, 256, 0, stream>>>(coords, aw0, ab0, aw1p, eb, ew, ab2, A);
    k_aggupd<<<256, 1024, 0, stream>>>(A, h_t, h_bf, coords, uw0, ub0,
                                       w0t, w1t, ub1, out);
}